// Round 19
// baseline (114.834 us; speedup 1.0000x reference)
//
#include <hip/hip_runtime.h>
#include <hip/hip_bf16.h>

// USM sharpen, fused 2-kernel MFMA. R13 base (96.4us, verified) + 3 safe deltas:
//   1. All f32->bf16 via COMPILER intrinsics (__float22bfloat162_rn /
//      __float2bfloat16) -> single v_cvt_pk_bf16_f32 HW ops the compiler can
//      schedule freely (R14's inline-asm blocked scheduling; R13's manual
//      bit-twiddle costs ~5 VALU/convert). Bit reinterpretation via
//      __builtin_memcpy (bit_cast rejects __hip_bfloat162 on this ROCm).
//   2. Epilogue img/res operands prefetched before the first barrier.
//   3. maskbuf dropped: K2 stages mask straight from res bf16 via the exact
//      bit-compare (u&0x7FFF)>0x3D20  <=>  |res|*255>10 (R9-verified).
//   K1 (PASS 0): img f32 --[hblur -> H(LDS alias) -> vblur]--> res bf16
//   K2 (PASS 1): mask(res) --[hblur -> H -> vblur]--> sm; out = img + sm*(sharp-img)
// Geometry (R13-verified): 64x64 tile/block, stage st[128][136p] bf16 row-major
// (y = y0-33+s, s<122 data + clamp), H[64][136p] aliased at st base (phase-C
// accs in regs across the alias barrier), 2 K-slices + g-predicated exact tap
// corrections (hblur: i=0/t=0 @c=16xs+7, i=15/t=50 @c=16xs+72; vblur: i=14/t=50
// @s=16ys+72, i=15/t=49,50 @s=16ys+72,73), R7 fragment convention, bijective
// chunked XCD swizzle (3072 = 8*384). LDS 34816 B -> 4 blocks/CU.

typedef __attribute__((ext_vector_type(8))) short bf16x8;
typedef __attribute__((ext_vector_type(4))) float f32x4;

constexpr int IMG = 512, NIMG = 48, K = 51;
constexpr int SP = 136;      // stage pitch: 68 dwords % 32 = 4 -> bank spread
constexpr int YP = 136;      // H pitch (aliased region)
constexpr int SROWS = 128;   // 122 data rows + 6 clamp
constexpr int SDATA = 122;

__device__ __forceinline__ float bf2f(unsigned short u) {
    return __builtin_bit_cast(float, (unsigned)u << 16);
}
__device__ __forceinline__ unsigned pk2bf(float lo, float hi) {  // v_cvt_pk_bf16_f32
    const __hip_bfloat162 h = __float22bfloat162_rn(float2{lo, hi});
    unsigned r;
    __builtin_memcpy(&r, &h, 4);
    return r;
}
__device__ __forceinline__ unsigned short s2bf(float f) {
    const __hip_bfloat16 h = __float2bfloat16(f);
    unsigned short r;
    __builtin_memcpy(&r, &h, 2);
    return r;
}
__device__ __forceinline__ int refl(int i) {
    i = i < 0 ? -i : i;
    return i >= IMG ? 2 * IMG - 2 - i : i;
}

template <int PASS>  // 0: img -> res ; 1: res -> out
__global__ __launch_bounds__(512, 8) void usm_kern(const float* __restrict__ img,
                                                   unsigned short* __restrict__ resbuf,
                                                   float* __restrict__ out,
                                                   const float* __restrict__ k1d) {
    __shared__ unsigned short st[SROWS * SP];      // 34816 B; H aliases its base
    unsigned short* const Hl = st;                 // H[64][YP] = 17408 B < st

    const int tid = threadIdx.x, lane = tid & 63;
    const int wv = __builtin_amdgcn_readfirstlane(tid >> 6);
    const int m16 = lane & 15, g = lane >> 4;

    const int id = blockIdx.x;
    const int sw = (id & 7) * 384 + (id >> 3);  // bijective XCD swizzle: 3072 = 8*384
    const int bz = sw >> 6, r6 = sw & 63, byy = r6 >> 3, bxx = r6 & 7;
    const int x0 = bxx * 64, y0 = byy * 64;
    const size_t base = (size_t)bz * (IMG * IMG);
    const float* __restrict__ imgb = img + base;
    unsigned short* __restrict__ resb = resbuf + base;
    float* __restrict__ outb = out + base;

    // ---- W bands in registers: a_v[rs][j]=g[32rs+8g+j-m16], a_h = idx+1 ----
    bf16x8 a_v[2], a_h[2];
#pragma unroll
    for (int rs = 0; rs < 2; ++rs) {
        float gt[9];
#pragma unroll
        for (int e = 0; e < 9; ++e) {
            const int t = 32 * rs + 8 * g + e - m16;
            gt[e] = ((unsigned)t < (unsigned)K) ? k1d[t] : 0.f;
        }
#pragma unroll
        for (int j = 0; j < 8; ++j) {
            a_v[rs][j] = (short)s2bf(gt[j]);
            a_h[rs][j] = (short)s2bf(gt[j + 1]);
        }
    }
    const float gg0 = k1d[0], gg49 = k1d[49], gg50 = k1d[50];  // uniform -> SGPR

    // ---- stage 128 rows x 128 cols (row-dense b128 writes) ----
    const bool xedge = (bxx == 0) | (bxx == 7);
    const int r0t = tid >> 4, c8 = (tid & 15) * 8;
#pragma unroll
    for (int j = 0; j < 4; ++j) {
        const int s = r0t + 32 * j;
        const int rowo = refl(y0 - 33 + min(s, SDATA - 1)) * IMG + (x0 - 32 + c8);
        unsigned pk[4];
        if (PASS == 0) {
            float v[8];
            if (!xedge) {
                const f32x4 f0 = *(const f32x4*)&imgb[rowo];
                const f32x4 f1 = *(const f32x4*)&imgb[rowo + 4];
#pragma unroll
                for (int e = 0; e < 4; ++e) { v[e] = f0[e]; v[e + 4] = f1[e]; }
            } else {
                const int rb = rowo - (x0 - 32 + c8);
#pragma unroll
                for (int e = 0; e < 8; ++e) v[e] = imgb[rb + refl(x0 - 32 + c8 + e)];
            }
#pragma unroll
            for (int w = 0; w < 4; ++w) pk[w] = pk2bf(v[2 * w], v[2 * w + 1]);
        } else {
            unsigned rw[4];
            if (!xedge) {
                const uint4 q4 = *(const uint4*)&resb[rowo];
                rw[0] = q4.x; rw[1] = q4.y; rw[2] = q4.z; rw[3] = q4.w;
            } else {
                const int rb = rowo - (x0 - 32 + c8);
#pragma unroll
                for (int w = 0; w < 4; ++w) {
                    const unsigned short e0 = resb[rb + refl(x0 - 32 + c8 + 2 * w)];
                    const unsigned short e1 = resb[rb + refl(x0 - 32 + c8 + 2 * w + 1)];
                    rw[w] = (unsigned)e0 | ((unsigned)e1 << 16);
                }
            }
#pragma unroll
            for (int w = 0; w < 4; ++w) {  // mask(|res|*255>10): exact bf16 bit-compare
                const unsigned lo = ((rw[w] & 0x7FFFu) > 0x3D20u) ? 0x3F80u : 0u;
                const unsigned hi = (((rw[w] >> 16) & 0x7FFFu) > 0x3D20u) ? 0x3F80u : 0u;
                pk[w] = lo | (hi << 16);
            }
        }
        *(uint4*)&st[s * SP + c8] = make_uint4(pk[0], pk[1], pk[2], pk[3]);
    }

    // ---- prefetch epilogue operands (consumed in phase D, 3 barriers later) ----
    float ivp[2][4];
    unsigned short rvp[2][4];
#pragma unroll
    for (int k2 = 0; k2 < 2; ++k2) {
        const int t = wv + 8 * k2;
        const int xs2 = t & 3, ys = t >> 2;
        const int xl = 16 * xs2 + m16, yl0 = 16 * ys + 4 * g;
#pragma unroll
        for (int q = 0; q < 4; ++q) {
            const int di = (y0 + yl0 + q) * IMG + (x0 + xl);
            ivp[k2][q] = imgb[di];
            if (PASS == 1) rvp[k2][q] = resb[di];
        }
    }
    __syncthreads();

    // ---- phase C: hblur, accumulators in registers ----
    f32x4 cacc[4];
#pragma unroll
    for (int k4 = 0; k4 < 4; ++k4) {
        const int t = wv + 8 * k4;
        const int xs = t & 3, yt = t >> 2;
        const int n = 16 * yt + m16;  // B col = stage row s
        f32x4 acc = {0.f, 0.f, 0.f, 0.f};
#pragma unroll
        for (int rs = 0; rs < 2; ++rs) {
            const bf16x8 b = *(const bf16x8*)&st[n * SP + 16 * xs + 8 + 32 * rs + 8 * g];
            acc = __builtin_amdgcn_mfma_f32_16x16x32_bf16(a_h[rs], b, acc, 0, 0, 0);
        }
        if (g == 0) acc[0] = fmaf(gg0,  bf2f(st[n * SP + 16 * xs + 7]),  acc[0]);  // i=0,  t=0
        if (g == 3) acc[3] = fmaf(gg50, bf2f(st[n * SP + 16 * xs + 72]), acc[3]);  // i=15, t=50
        cacc[k4] = acc;
    }
    __syncthreads();  // st fully consumed; H may overwrite its base

    // ---- H write (aliased into st), packed HW converts ----
#pragma unroll
    for (int k4 = 0; k4 < 4; ++k4) {
        const int t = wv + 8 * k4;
        const int xs = t & 3, yt = t >> 2;
        const int n = 16 * yt + m16;
        const unsigned u01 = pk2bf(cacc[k4][0], cacc[k4][1]);
        const unsigned u23 = pk2bf(cacc[k4][2], cacc[k4][3]);
        Hl[(16 * xs + 4 * g + 0) * YP + n] = (unsigned short)u01;
        Hl[(16 * xs + 4 * g + 1) * YP + n] = (unsigned short)(u01 >> 16);
        Hl[(16 * xs + 4 * g + 2) * YP + n] = (unsigned short)u23;
        Hl[(16 * xs + 4 * g + 3) * YP + n] = (unsigned short)(u23 >> 16);
    }
    __syncthreads();

    // ---- phase D: vblur + fused epilogue (prefetched operands) ----
#pragma unroll
    for (int k2 = 0; k2 < 2; ++k2) {
        const int t = wv + 8 * k2;
        const int xs2 = t & 3, ys = t >> 2;
        const int xl = 16 * xs2 + m16;
        f32x4 acc = {0.f, 0.f, 0.f, 0.f};
#pragma unroll
        for (int rs = 0; rs < 2; ++rs) {
            const bf16x8 b = *(const bf16x8*)&Hl[xl * YP + 16 * ys + 8 + 32 * rs + 8 * g];
            acc = __builtin_amdgcn_mfma_f32_16x16x32_bf16(a_v[rs], b, acc, 0, 0, 0);
        }
        if (g == 3) {
            const float h72 = bf2f(Hl[xl * YP + 16 * ys + 72]);
            const float h73 = bf2f(Hl[xl * YP + 16 * ys + 73]);
            acc[2] = fmaf(gg50, h72, acc[2]);                   // i=14, t=50
            acc[3] = fmaf(gg49, h72, fmaf(gg50, h73, acc[3]));  // i=15, t=49,50
        }
        const int yl0 = 16 * ys + 4 * g;
#pragma unroll
        for (int q = 0; q < 4; ++q) {
            const int di = (y0 + yl0 + q) * IMG + (x0 + xl);
            const float iv = ivp[k2][q];
            if (PASS == 0) {
                resb[di] = s2bf(iv - acc[q]);
            } else {
                const float rv = bf2f(rvp[k2][q]);
                float sharp = fmaf(0.5f, rv, iv);
                sharp = fminf(fmaxf(sharp, 0.f), 1.f);
                outb[di] = fmaf(acc[q], sharp - iv, iv);  // img + sm*(sharp-img)
            }
        }
    }
}

extern "C" void kernel_launch(void* const* d_in, const int* in_sizes, int n_in,
                              void* d_out, int out_size, void* d_ws, size_t ws_size,
                              hipStream_t stream) {
    (void)in_sizes; (void)n_in; (void)out_size; (void)ws_size;
    const float* img = (const float*)d_in[0];
    const float* k1d = (const float*)d_in[1];
    float* out = (float*)d_out;
    unsigned short* rs = (unsigned short*)d_ws;  // 25165824 B

    const dim3 grid(NIMG * 64);  // 3072 blocks x 512 threads

    usm_kern<0><<<grid, 512, 0, stream>>>(img, rs, out, k1d);
    usm_kern<1><<<grid, 512, 0, stream>>>(img, rs, out, k1d);
}

// Round 20
// 91.607 us; speedup vs baseline: 1.2535x; 1.2535x over previous
//
#include <hip/hip_runtime.h>
#include <hip/hip_bf16.h>

// USM sharpen, fused 2-kernel MFMA. R13 skeleton with ONE geometry change:
// tall 64(x)x128(y) tiles (1536 blocks) -> stage halo amplification 4.0 -> 2.9,
// and K1's epilogue reads the img center from the staged LDS copy (saved to
// regs before the alias barrier) instead of re-reading 50 MB from global.
//   K1 (PASS 0): img f32 --[hblur -> H(LDS alias) -> vblur]--> res bf16
//   K2 (PASS 1): mask(res) --[hblur -> H -> vblur]--> sm; out = img + sm*(sharp-img)
// Geometry: stage st[192 rows][136p] bf16 row-major (y = y0-33+s, s<186 data,
// 186..191 clamp-filled finite; x = x0-32+c, c in [0,128) -- SAME col layout
// and pitch as R13, phase-C bank structure untouched). H[64 x'][200p s]
// aliased at st base (pitch 200 = 100 dwords == 4 mod 32, same verified bank
// residue as R13's 136). Phase C: 48 MFMA tiles (4 xs x 12 yt), 6/wave,
// accumulators in regs across the alias barrier. Phase D: 32 tiles (4 x 8),
// 4/wave. 2 K-slices + g-predicated exact tap corrections (hblur: i=0/t=0
// @c=16xs+7, i=15/t=50 @c=16xs+72; vblur: i=14/t=50 @s=16ys+72, i=15/t=49,50
// @s=16ys+72,73) -- all R13-verified forms. H cols n>=186 are garbage-but-
// finite and never read by phase D (taps s<=185). Mask via exact bf16
// bit-compare (u&0x7FFF)>0x3D20 <=> |res|*255>10. Bijective XCD swizzle
// (1536 = 8*192). LDS 52224 B -> 3 blocks/CU.

typedef __attribute__((ext_vector_type(8))) short bf16x8;
typedef __attribute__((ext_vector_type(4))) float f32x4;

constexpr int IMG = 512, NIMG = 48, K = 51;
constexpr int SP = 136;      // stage pitch (68 dwords == 4 mod 32)
constexpr int YP = 200;      // H pitch (100 dwords == 4 mod 32)
constexpr int SROWS = 192;   // staged row slots
constexpr int SDATA = 186;   // real data rows (33 + 128 + 25)

__device__ __forceinline__ float bf2f(unsigned short u) {
    return __builtin_bit_cast(float, (unsigned)u << 16);
}
__device__ __forceinline__ unsigned short f2bf(float f) {
    unsigned u = __builtin_bit_cast(unsigned, f);
    u += 0x7FFF + ((u >> 16) & 1);  // RNE, finite inputs only
    return (unsigned short)(u >> 16);
}
__device__ __forceinline__ int refl(int i) {
    i = i < 0 ? -i : i;
    return i >= IMG ? 2 * IMG - 2 - i : i;
}

template <int PASS>  // 0: img -> res ; 1: res -> out
__global__ __launch_bounds__(512, 6) void usm_kern(const float* __restrict__ img,
                                                   unsigned short* __restrict__ resbuf,
                                                   float* __restrict__ out,
                                                   const float* __restrict__ k1d) {
    __shared__ unsigned short st[SROWS * SP];      // 52224 B; H aliases its base
    unsigned short* const Hl = st;                 // H[64][YP] = 25600 shorts < st

    const int tid = threadIdx.x, lane = tid & 63;
    const int wv = __builtin_amdgcn_readfirstlane(tid >> 6);
    const int m16 = lane & 15, g = lane >> 4;

    const int id = blockIdx.x;
    const int sw = (id & 7) * 192 + (id >> 3);  // bijective XCD swizzle: 1536 = 8*192
    const int bz = sw >> 5, r5 = sw & 31, byy = r5 >> 3, bxx = r5 & 7;
    const int x0 = bxx * 64, y0 = byy * 128;
    const size_t base = (size_t)bz * (IMG * IMG);
    const float* __restrict__ imgb = img + base;
    unsigned short* __restrict__ resb = resbuf + base;
    float* __restrict__ outb = out + base;

    // ---- W bands in registers: a_v[rs][j]=g[32rs+8g+j-m16], a_h = idx+1 ----
    bf16x8 a_v[2], a_h[2];
#pragma unroll
    for (int rs = 0; rs < 2; ++rs) {
        float gt[9];
#pragma unroll
        for (int e = 0; e < 9; ++e) {
            const int t = 32 * rs + 8 * g + e - m16;
            gt[e] = ((unsigned)t < (unsigned)K) ? k1d[t] : 0.f;
        }
#pragma unroll
        for (int j = 0; j < 8; ++j) {
            a_v[rs][j] = (short)f2bf(gt[j]);
            a_h[rs][j] = (short)f2bf(gt[j + 1]);
        }
    }
    const float gg0 = k1d[0], gg49 = k1d[49], gg50 = k1d[50];  // uniform -> SGPR

    // ---- stage 192 row-slots x 128 cols (row-dense b128 writes) ----
    const bool xedge = (bxx == 0) | (bxx == 7);
    const int r0t = tid >> 4, c8 = (tid & 15) * 8;
#pragma unroll
    for (int j = 0; j < 6; ++j) {
        const int s = r0t + 32 * j;
        const int rowo = refl(y0 - 33 + min(s, SDATA - 1)) * IMG + (x0 - 32 + c8);
        unsigned pk[4];
        if (PASS == 0) {
            float v[8];
            if (!xedge) {
                const f32x4 f0 = *(const f32x4*)&imgb[rowo];
                const f32x4 f1 = *(const f32x4*)&imgb[rowo + 4];
#pragma unroll
                for (int e = 0; e < 4; ++e) { v[e] = f0[e]; v[e + 4] = f1[e]; }
            } else {
                const int rb = rowo - (x0 - 32 + c8);
#pragma unroll
                for (int e = 0; e < 8; ++e) v[e] = imgb[rb + refl(x0 - 32 + c8 + e)];
            }
#pragma unroll
            for (int w = 0; w < 4; ++w)
                pk[w] = (unsigned)f2bf(v[2 * w]) | ((unsigned)f2bf(v[2 * w + 1]) << 16);
        } else {
            unsigned rw[4];
            if (!xedge) {
                const uint4 q4 = *(const uint4*)&resb[rowo];
                rw[0] = q4.x; rw[1] = q4.y; rw[2] = q4.z; rw[3] = q4.w;
            } else {
                const int rb = rowo - (x0 - 32 + c8);
#pragma unroll
                for (int w = 0; w < 4; ++w) {
                    const unsigned short e0 = resb[rb + refl(x0 - 32 + c8 + 2 * w)];
                    const unsigned short e1 = resb[rb + refl(x0 - 32 + c8 + 2 * w + 1)];
                    rw[w] = (unsigned)e0 | ((unsigned)e1 << 16);
                }
            }
#pragma unroll
            for (int w = 0; w < 4; ++w) {  // mask(|res|*255>10): exact bf16 bit-compare
                const unsigned lo = ((rw[w] & 0x7FFFu) > 0x3D20u) ? 0x3F80u : 0u;
                const unsigned hi = (((rw[w] >> 16) & 0x7FFFu) > 0x3D20u) ? 0x3F80u : 0u;
                pk[w] = lo | (hi << 16);
            }
        }
        *(uint4*)&st[s * SP + c8] = make_uint4(pk[0], pk[1], pk[2], pk[3]);
    }
    __syncthreads();

    // ---- phase C: hblur, 48 tiles (4 xs x 12 yt), 6/wave, accs in regs ----
    f32x4 cacc[6];
#pragma unroll
    for (int k6 = 0; k6 < 6; ++k6) {
        const int t = wv + 8 * k6;
        const int xs = t & 3, yt = t >> 2;
        const int n = 16 * yt + m16;  // B col = stage row s
        f32x4 acc = {0.f, 0.f, 0.f, 0.f};
#pragma unroll
        for (int rs = 0; rs < 2; ++rs) {
            const bf16x8 b = *(const bf16x8*)&st[n * SP + 16 * xs + 8 + 32 * rs + 8 * g];
            acc = __builtin_amdgcn_mfma_f32_16x16x32_bf16(a_h[rs], b, acc, 0, 0, 0);
        }
        if (g == 0) acc[0] = fmaf(gg0,  bf2f(st[n * SP + 16 * xs + 7]),  acc[0]);  // i=0,  t=0
        if (g == 3) acc[3] = fmaf(gg50, bf2f(st[n * SP + 16 * xs + 72]), acc[3]);  // i=15, t=50
        cacc[k6] = acc;
    }

    // ---- K1: save img center (staged bf16) to regs before the alias clobber ----
    unsigned short civ[4][4];
    if (PASS == 0) {
#pragma unroll
        for (int k4 = 0; k4 < 4; ++k4) {
            const int t = wv + 8 * k4;
            const int xs2 = t & 3, ys = t >> 2;
            const int xl = 16 * xs2 + m16;
#pragma unroll
            for (int q = 0; q < 4; ++q)
                civ[k4][q] = st[(33 + 16 * ys + 4 * g + q) * SP + xl + 32];
        }
    }
    __syncthreads();  // st fully consumed; H may overwrite its base

    // ---- H write (aliased into st) ----
#pragma unroll
    for (int k6 = 0; k6 < 6; ++k6) {
        const int t = wv + 8 * k6;
        const int xs = t & 3, yt = t >> 2;
        const int n = 16 * yt + m16;
#pragma unroll
        for (int q = 0; q < 4; ++q)
            Hl[(16 * xs + 4 * g + q) * YP + n] = f2bf(cacc[k6][q]);
    }
    __syncthreads();

    // ---- phase D: vblur + fused epilogue, 32 tiles (4 x 8), 4/wave ----
#pragma unroll
    for (int k4 = 0; k4 < 4; ++k4) {
        const int t = wv + 8 * k4;
        const int xs2 = t & 3, ys = t >> 2;
        const int xl = 16 * xs2 + m16;
        f32x4 acc = {0.f, 0.f, 0.f, 0.f};
#pragma unroll
        for (int rs = 0; rs < 2; ++rs) {
            const bf16x8 b = *(const bf16x8*)&Hl[xl * YP + 16 * ys + 8 + 32 * rs + 8 * g];
            acc = __builtin_amdgcn_mfma_f32_16x16x32_bf16(a_v[rs], b, acc, 0, 0, 0);
        }
        if (g == 3) {
            const float h72 = bf2f(Hl[xl * YP + 16 * ys + 72]);
            const float h73 = bf2f(Hl[xl * YP + 16 * ys + 73]);
            acc[2] = fmaf(gg50, h72, acc[2]);                   // i=14, t=50
            acc[3] = fmaf(gg49, h72, fmaf(gg50, h73, acc[3]));  // i=15, t=49,50
        }
        const int yl0 = 16 * ys + 4 * g;
#pragma unroll
        for (int q = 0; q < 4; ++q) {
            const int di = (y0 + yl0 + q) * IMG + (x0 + xl);
            if (PASS == 0) {
                const float iv = bf2f(civ[k4][q]);   // staged img center, no global read
                resb[di] = f2bf(iv - acc[q]);
            } else {
                const float iv = imgb[di];           // L2-hot (tile just staged)
                const float rv = bf2f(resb[di]);
                float sharp = fmaf(0.5f, rv, iv);
                sharp = fminf(fmaxf(sharp, 0.f), 1.f);
                outb[di] = fmaf(acc[q], sharp - iv, iv);  // img + sm*(sharp-img)
            }
        }
    }
}

extern "C" void kernel_launch(void* const* d_in, const int* in_sizes, int n_in,
                              void* d_out, int out_size, void* d_ws, size_t ws_size,
                              hipStream_t stream) {
    (void)in_sizes; (void)n_in; (void)out_size; (void)ws_size;
    const float* img = (const float*)d_in[0];
    const float* k1d = (const float*)d_in[1];
    float* out = (float*)d_out;
    unsigned short* rs = (unsigned short*)d_ws;  // 25165824 B

    const dim3 grid(NIMG * 32);  // 1536 blocks x 512 threads

    usm_kern<0><<<grid, 512, 0, stream>>>(img, rs, out, k1d);
    usm_kern<1><<<grid, 512, 0, stream>>>(img, rs, out, k1d);
}